// Round 11
// baseline (88.097 us; speedup 1.0000x reference)
//
#include <hip/hip_runtime.h>

#define S 128
#define SS (S*S)
#define B 8
#define BSS (B*SS)              // 131072 floats per [b][128][128] stack
#define NEG_INF (-3.402823466e+38f)

// ws layout (float elements). NO global atomics, NO memset.
// ACC_LOSS: [b][half] topo partials (16)
// ACC_DICE: [bid(512)][{at,aa,tt}] (1536)
// PA : [vol][b][i][j]  exact                 (2*BSS)
// PBP: [vol][b][ic=8][j][k] partials         (2*8*8*SS)
// PCP: [vol][b][jc=8][i][k] partials         (2*8*8*SS)
#define ACC_LOSS 0
#define ACC_DICE 16
#define PA   2048
#define PBP  (PA  + 2*BSS)
#define PCP  (PBP + 2*8*8*SS)

// mapf(-FLT_MAX) — safe LDS-atomic init value
#define MAPF_NEGMAX 0x00800000u

__device__ __forceinline__ unsigned mapf(float f) {
  unsigned u = __float_as_uint(f);
  return (u & 0x80000000u) ? ~u : (u | 0x80000000u);
}
__device__ __forceinline__ float unmapf(unsigned u) {
  return (u & 0x80000000u) ? __uint_as_float(u & 0x7FFFFFFFu) : __uint_as_float(~u);
}
__device__ __forceinline__ float4 max4(float4 a, float4 b) {
  return make_float4(fmaxf(a.x,b.x), fmaxf(a.y,b.y), fmaxf(a.z,b.z), fmaxf(a.w,b.w));
}
__device__ __forceinline__ float hmax4(float4 a) {
  return fmaxf(fmaxf(a.x,a.y), fmaxf(a.z,a.w));
}
__device__ __forceinline__ float4 shflx4(float4 v, int m) {
  return make_float4(__shfl_xor(v.x,m,64), __shfl_xor(v.y,m,64),
                     __shfl_xor(v.z,m,64), __shfl_xor(v.w,m,64));
}

// Phase 1: stream channel-1 of both volumes once; projections + dice sums.
// Grid (jc=8, ic=8, b=8) = 512 blocks, 512 threads, 4 blocks/CU (32 waves/CU).
// Block tile: 16 i x 16 j x 128 k. Thread = (jr = tid>>5 in 0..15, kl = tid&31).
// ZERO in-loop barriers (R10 structure): Pc via LDS atomicMax on mapped uints,
// Pa row-maxes buffered in LDS. High occupancy is the experiment (R6/R9's
// co-residency regressions were barrier-convoy artifacts; no barriers here).
__global__ __launch_bounds__(512, 8) void proj_dice_kernel(
    const float* __restrict__ gin, const float* __restrict__ gtg,
    float* __restrict__ ws)
{
  const int jc  = blockIdx.x;   // 0..7   j chunk of 16
  const int ic  = blockIdx.y;   // 0..7   i chunk of 16
  const int b   = blockIdx.z;   // 0..7
  const int tid = threadIdx.x;
  const int jr  = tid >> 5;     // 0..15
  const int kl  = tid & 31;     // 0..31
  const int j   = (jc << 4) + jr;
  const int i0  = ic << 4;
  const int k0  = kl << 2;
  const int w   = tid >> 6;     // wave 0..7
  const int h   = (tid >> 5) & 1;

  const float* __restrict__ xin = gin + (size_t)(2*b + 1) * (size_t)(S*SS);
  const float* __restrict__ xtg = gtg + (size_t)(2*b + 1) * (size_t)(S*SS);

  float* paI = ws + PA + (size_t)(0*B + b)*SS;
  float* paT = ws + PA + (size_t)(1*B + b)*SS;
  float* pbI = ws + PBP + (size_t)((0*B + b)*8 + ic)*SS;
  float* pbT = ws + PBP + (size_t)((1*B + b)*8 + ic)*SS;
  float* pcI = ws + PCP + (size_t)((0*B + b)*8 + jc)*SS;
  float* pcT = ws + PCP + (size_t)((1*B + b)*8 + jc)*SS;

  __shared__ unsigned lpc[2][16][S];   // 16 KB: Pc accum, mapped-uint atomicMax
  __shared__ float    lpa[2][16][16];  //  2 KB: Pa row maxes
  __shared__ float    dred[8][3];

  // init lpc (4096 uints / 512 threads = 8 each)
  {
    uint4* p = (uint4*)(&lpc[0][0][0]) + tid*2;
    const uint4 v = make_uint4(MAPF_NEGMAX, MAPF_NEGMAX, MAPF_NEGMAX, MAPF_NEGMAX);
    p[0] = v; p[1] = v;
  }
  __syncthreads();

  float4 pba = make_float4(NEG_INF, NEG_INF, NEG_INF, NEG_INF);
  float4 pbt = pba;
  float s_at = 0.f, s_aa = 0.f, s_tt = 0.f;

  for (int r = 0; r < 4; ++r) {
    #pragma unroll
    for (int q = 0; q < 4; ++q) {
      const int ii = (r << 2) + q;
      const int i  = i0 + ii;
      const size_t off = (size_t)i*SS + (size_t)j*S + k0;
      const float4 a = *(const float4*)(xin + off);
      const float4 t = *(const float4*)(xtg + off);

      s_at = fmaf(a.x,t.x, fmaf(a.y,t.y, fmaf(a.z,t.z, fmaf(a.w,t.w, s_at))));
      s_aa = fmaf(a.x,a.x, fmaf(a.y,a.y, fmaf(a.z,a.z, fmaf(a.w,a.w, s_aa))));
      s_tt = fmaf(t.x,t.x, fmaf(t.y,t.y, fmaf(t.z,t.z, fmaf(t.w,t.w, s_tt))));

      // Pb accumulate over i (register)
      pba = max4(pba, a);
      pbt = max4(pbt, t);

      // Pa[i][j]: max over k = 32 kl lanes of this half-wave -> LDS buffer
      float rma = hmax4(a), rmt = hmax4(t);
      #pragma unroll
      for (int m = 16; m >= 1; m >>= 1) {
        rma = fmaxf(rma, __shfl_xor(rma, m, 64));
        rmt = fmaxf(rmt, __shfl_xor(rmt, m, 64));
      }
      if (kl == 0) { lpa[0][ii][jr] = rma; lpa[1][ii][jr] = rmt; }

      // Pc: combine the wave's jr-pair, then LDS atomicMax (no barrier)
      const float4 pca = max4(a, shflx4(a, 32));
      const float4 pct = max4(t, shflx4(t, 32));
      if (h == 0) {
        atomicMax(&lpc[0][ii][k0+0], mapf(pca.x));
        atomicMax(&lpc[0][ii][k0+1], mapf(pca.y));
        atomicMax(&lpc[0][ii][k0+2], mapf(pca.z));
        atomicMax(&lpc[0][ii][k0+3], mapf(pca.w));
        atomicMax(&lpc[1][ii][k0+0], mapf(pct.x));
        atomicMax(&lpc[1][ii][k0+1], mapf(pct.y));
        atomicMax(&lpc[1][ii][k0+2], mapf(pct.z));
        atomicMax(&lpc[1][ii][k0+3], mapf(pct.w));
      }
    }
  }

  __syncthreads();   // all LDS atomics + lpa writes complete

  // Pc tail: 2t x 16ii x 128k = 4096 floats, 8 per thread (two float4 stores)
  {
    const int t   = tid >> 8;
    const int rem = tid & 255;
    const int ii  = rem >> 4;
    const int k8  = (rem & 15) << 3;
    float* dst = (t ? pcT : pcI) + (size_t)(i0+ii)*S + k8;
    const float4 v0 = make_float4(unmapf(lpc[t][ii][k8+0]), unmapf(lpc[t][ii][k8+1]),
                                  unmapf(lpc[t][ii][k8+2]), unmapf(lpc[t][ii][k8+3]));
    const float4 v1 = make_float4(unmapf(lpc[t][ii][k8+4]), unmapf(lpc[t][ii][k8+5]),
                                  unmapf(lpc[t][ii][k8+6]), unmapf(lpc[t][ii][k8+7]));
    *(float4*)(dst)     = v0;
    *(float4*)(dst + 4) = v1;
  }
  // Pa tail: 2t x 16ii x 16jr = 512 floats, 1 per thread
  {
    const int t   = tid >> 8;
    const int rem = tid & 255;
    const int ii  = rem >> 4;
    const int jj  = rem & 15;
    (t ? paT : paI)[(size_t)(i0+ii)*S + (jc << 4) + jj] = lpa[t][ii][jj];
  }

  // flush Pb partial [j][k] (max over this block's 16 i's) — float4 store
  *(float4*)(pbI + j*S + k0) = pba;
  *(float4*)(pbT + j*S + k0) = pbt;

  // dice partial: wave-reduce then per-block plain store (no atomics)
  float v0 = s_at, v1 = s_aa, v2 = s_tt;
  #pragma unroll
  for (int m = 32; m >= 1; m >>= 1) {
    v0 += __shfl_xor(v0, m, 64);
    v1 += __shfl_xor(v1, m, 64);
    v2 += __shfl_xor(v2, m, 64);
  }
  if ((tid & 63) == 0) { dred[w][0] = v0; dred[w][1] = v1; dred[w][2] = v2; }
  __syncthreads();
  if (tid == 0) {
    float a0 = 0.f, a1 = 0.f, a2 = 0.f;
    #pragma unroll
    for (int rr = 0; rr < 8; ++rr) { a0 += dred[rr][0]; a1 += dred[rr][1]; a2 += dred[rr][2]; }
    const int bid = jc + 8*ic + 64*b;   // 64 blocks per b
    ws[ACC_DICE + bid*3 + 0] = a0;
    ws[ACC_DICE + bid*3 + 1] = a1;
    ws[ACC_DICE + bid*3 + 2] = a2;
  }
}

// Phase 2: fused partial-reduce + pyramid max-pool at all 5 scales.
// Grid (half=2, b=8) = 16 blocks, 128 threads. Each block owns a 128x64
// column-half (all pooling windows <=32 cols stay inside a half).
// Thread = (tr = tid>>3 in 0..15, tc = tid&7), owns an 8x8 tile.
// k=2,4,8 thread-local; k=16 via shfl_xor {1,8}; k=32 via {2,16}.
__global__ __launch_bounds__(128) void pool_loss_kernel(float* __restrict__ ws)
{
  const int half = blockIdx.x;   // 0..1
  const int b    = blockIdx.y;
  const int tid  = threadIdx.x;
  const int tr   = tid >> 3;     // 0..15
  const int tc   = tid & 7;      // 0..7
  const int r0   = tr << 3;
  const int c0   = (half << 6) + (tc << 3);

  float s2[2][4][4];
  float s4[2][2][2];
  float s8[2], s16[2], s32[2];
  #pragma unroll
  for (int v = 0; v < 2; ++v) {
    #pragma unroll
    for (int y = 0; y < 4; ++y)
      #pragma unroll
      for (int x = 0; x < 4; ++x) s2[v][y][x] = 0.f;
    #pragma unroll
    for (int y = 0; y < 2; ++y)
      #pragma unroll
      for (int x = 0; x < 2; ++x) s4[v][y][x] = 0.f;
    s8[v] = 0.f; s16[v] = 0.f; s32[v] = 0.f;
  }

  #pragma unroll
  for (int t = 0; t < 3; ++t) {
    #pragma unroll
    for (int vol = 0; vol < 2; ++vol) {
      const int np = (t == 0) ? 1 : 8;
      const float* base =
        (t == 0) ? ws + PA  + (size_t)(vol*B + b)*SS :
        (t == 1) ? ws + PBP + (size_t)((vol*B + b)*8)*SS :
                   ws + PCP + (size_t)((vol*B + b)*8)*SS;
      float tile[8][8];
      #pragma unroll
      for (int r = 0; r < 8; ++r)
        #pragma unroll
        for (int c = 0; c < 8; ++c) tile[r][c] = NEG_INF;
      for (int p = 0; p < np; ++p) {
        const float* m = base + (size_t)p*SS;
        #pragma unroll
        for (int r = 0; r < 8; ++r) {
          const float4 a = *(const float4*)(m + (size_t)(r0 + r)*S + c0);
          const float4 c = *(const float4*)(m + (size_t)(r0 + r)*S + c0 + 4);
          tile[r][0]=fmaxf(tile[r][0],a.x); tile[r][1]=fmaxf(tile[r][1],a.y);
          tile[r][2]=fmaxf(tile[r][2],a.z); tile[r][3]=fmaxf(tile[r][3],a.w);
          tile[r][4]=fmaxf(tile[r][4],c.x); tile[r][5]=fmaxf(tile[r][5],c.y);
          tile[r][6]=fmaxf(tile[r][6],c.z); tile[r][7]=fmaxf(tile[r][7],c.w);
        }
      }
      float m2[4][4];
      #pragma unroll
      for (int y = 0; y < 4; ++y)
        #pragma unroll
        for (int x = 0; x < 4; ++x) {
          m2[y][x] = fmaxf(fmaxf(tile[2*y][2*x], tile[2*y][2*x+1]),
                           fmaxf(tile[2*y+1][2*x], tile[2*y+1][2*x+1]));
          s2[vol][y][x] += m2[y][x];
        }
      float m4[2][2];
      #pragma unroll
      for (int y = 0; y < 2; ++y)
        #pragma unroll
        for (int x = 0; x < 2; ++x) {
          m4[y][x] = fmaxf(fmaxf(m2[2*y][2*x], m2[2*y][2*x+1]),
                           fmaxf(m2[2*y+1][2*x], m2[2*y+1][2*x+1]));
          s4[vol][y][x] += m4[y][x];
        }
      float m8 = fmaxf(fmaxf(m4[0][0], m4[0][1]), fmaxf(m4[1][0], m4[1][1]));
      s8[vol] += m8;
      float m16 = m8;                           // 16x16 = 2x2 tiles: tc^1, tr^1
      m16 = fmaxf(m16, __shfl_xor(m16, 1, 64));
      m16 = fmaxf(m16, __shfl_xor(m16, 8, 64));
      s16[vol] += m16;
      float m32 = m16;                          // 32x32 = 4x4 tiles: +tc^2, tr^2
      m32 = fmaxf(m32, __shfl_xor(m32, 2, 64));
      m32 = fmaxf(m32, __shfl_xor(m32, 16, 64));
      s32[vol] += m32;
    }
  }

  const float w0 = 1.f/(5.f*8.f*64.f*64.f);
  const float w1 = 1.f/(5.f*8.f*32.f*32.f);
  const float w2 = 1.f/(5.f*8.f*16.f*16.f);
  const float w3 = 1.f/(5.f*8.f*8.f*8.f);
  const float w4 = 1.f/(5.f*8.f*4.f*4.f);

  float l0 = 0.f;
  #pragma unroll
  for (int y = 0; y < 4; ++y)
    #pragma unroll
    for (int x = 0; x < 4; ++x) l0 += fabsf(s2[1][y][x] - s2[0][y][x]);
  float l1 = 0.f;
  #pragma unroll
  for (int y = 0; y < 2; ++y)
    #pragma unroll
    for (int x = 0; x < 2; ++x) l1 += fabsf(s4[1][y][x] - s4[0][y][x]);
  float part = l0*w0 + l1*w1 + fabsf(s8[1] - s8[0])*w2;
  if ((tid & 0x09) == 0) part += fabsf(s16[1] - s16[0])*w3;   // tc,tr even
  if ((tid & 0x1B) == 0) part += fabsf(s32[1] - s32[0])*w4;   // tc,tr %4==0

  #pragma unroll
  for (int m = 32; m >= 1; m >>= 1) part += __shfl_xor(part, m, 64);
  __shared__ float red[2];
  if ((tid & 63) == 0) red[tid >> 6] = part;
  __syncthreads();
  if (tid == 0) ws[ACC_LOSS + (b << 1) + half] = red[0] + red[1];
}

// Phase 3: combine. 512 threads; wave w reduces the 64 dice partials of b=w.
__global__ __launch_bounds__(512) void finalize_kernel(
    const float* __restrict__ ws, float* __restrict__ out)
{
  const int tid = threadIdx.x;
  const int w = tid >> 6;
  __shared__ float fd[8];

  float v0 = ws[ACC_DICE + tid*3 + 0];
  float v1 = ws[ACC_DICE + tid*3 + 1];
  float v2 = ws[ACC_DICE + tid*3 + 2];
  #pragma unroll
  for (int m = 32; m >= 1; m >>= 1) {
    v0 += __shfl_xor(v0, m, 64);
    v1 += __shfl_xor(v1, m, 64);
    v2 += __shfl_xor(v2, m, 64);
  }
  if ((tid & 63) == 0) fd[w] = (2.f*v0 + 1e-6f) / (v1 + v2);
  __syncthreads();
  if (tid == 0) {
    float topo = 0.f, dsum = 0.f;
    #pragma unroll
    for (int x = 0; x < 16; ++x) topo += ws[ACC_LOSS + x];
    #pragma unroll
    for (int b = 0; b < B; ++b) dsum += fd[b];
    out[0] = topo + (1.f - dsum / (float)B);
  }
}

extern "C" void kernel_launch(void* const* d_in, const int* in_sizes, int n_in,
                              void* d_out, int out_size, void* d_ws, size_t ws_size,
                              hipStream_t stream)
{
  const float* gin = (const float*)d_in[0];
  const float* gtg = (const float*)d_in[1];
  float* ws  = (float*)d_ws;
  float* out = (float*)d_out;

  dim3 g1(8, 8, B);
  proj_dice_kernel<<<g1, dim3(512), 0, stream>>>(gin, gtg, ws);

  pool_loss_kernel<<<dim3(2, B), dim3(128), 0, stream>>>(ws);

  finalize_kernel<<<1, dim3(512), 0, stream>>>(ws, out);
}

// Round 12
// 53.616 us; speedup vs baseline: 1.6431x; 1.6431x over previous
//
#include <hip/hip_runtime.h>

#define S 128
#define SS (S*S)
#define B 8
#define BSS (B*SS)              // 131072 floats per [b][128][128] stack
#define NEG_INF (-3.402823466e+38f)

// ws layout (float elements). NO global atomics, NO memset.
// ACC_LOSS: [b] topo partials (8)
// ACC_DICE: [bid(256)][{at,aa,tt}]
// PA : [vol][b][i][j]  exact                 (2*BSS)
// PBP: [vol][b][ic=8][j][k] partials         (2*8*8*SS)
// PCP: [vol][b][jc=4][i][k] partials         (2*8*4*SS)
#define ACC_LOSS 0
#define ACC_DICE 8
#define PA   1024
#define PBP  (PA  + 2*BSS)
#define PCP  (PBP + 2*8*8*SS)

// mapf(-FLT_MAX) — safe LDS-atomic init value
#define MAPF_NEGMAX 0x00800000u

__device__ __forceinline__ unsigned mapf(float f) {
  unsigned u = __float_as_uint(f);
  return (u & 0x80000000u) ? ~u : (u | 0x80000000u);
}
__device__ __forceinline__ float unmapf(unsigned u) {
  return (u & 0x80000000u) ? __uint_as_float(u & 0x7FFFFFFFu) : __uint_as_float(~u);
}
__device__ __forceinline__ float4 max4(float4 a, float4 b) {
  return make_float4(fmaxf(a.x,b.x), fmaxf(a.y,b.y), fmaxf(a.z,b.z), fmaxf(a.w,b.w));
}
__device__ __forceinline__ float hmax4(float4 a) {
  return fmaxf(fmaxf(a.x,a.y), fmaxf(a.z,a.w));
}
__device__ __forceinline__ float4 shflx4(float4 v, int m) {
  return make_float4(__shfl_xor(v.x,m,64), __shfl_xor(v.y,m,64),
                     __shfl_xor(v.z,m,64), __shfl_xor(v.w,m,64));
}

// Phase 1: stream channel-1 of both volumes once; projections + dice sums.
// Grid (jc=4, ic=8, b=8) = 256 blocks, 1024 threads (R10 skeleton, proven).
// Thread = (jr = tid>>5, kl = tid&31). ZERO in-loop barriers.
// R12 deltas vs R10:
//  - lpc permuted: k=4q+c stored at element c*32+q -> atomic lanes hit
//    consecutive banks (conflict-free; was 4-way stride-4).
//  - h-split: wave lanes 0-31 atomic the input plane, 32-63 the target
//    plane -> 4 full-wave atomics/i (was 8 half-wave).
//  - loads batched 4 i's ahead in registers (plain code, no fences).
__global__ __launch_bounds__(1024, 4) void proj_dice_kernel(
    const float* __restrict__ gin, const float* __restrict__ gtg,
    float* __restrict__ ws)
{
  const int jc  = blockIdx.x;   // 0..3   j chunk of 32
  const int ic  = blockIdx.y;   // 0..7   i chunk of 16
  const int b   = blockIdx.z;   // 0..7
  const int tid = threadIdx.x;
  const int jr  = tid >> 5;     // 0..31
  const int kl  = tid & 31;     // 0..31
  const int j   = (jc << 5) + jr;
  const int i0  = ic << 4;
  const int k0  = kl << 2;
  const int w   = tid >> 6;     // wave 0..15
  const int h   = (tid >> 5) & 1;

  const float* __restrict__ xin = gin + (size_t)(2*b + 1) * (size_t)(S*SS);
  const float* __restrict__ xtg = gtg + (size_t)(2*b + 1) * (size_t)(S*SS);

  float* paI = ws + PA + (size_t)(0*B + b)*SS;
  float* paT = ws + PA + (size_t)(1*B + b)*SS;
  float* pbI = ws + PBP + (size_t)((0*B + b)*8 + ic)*SS;
  float* pbT = ws + PBP + (size_t)((1*B + b)*8 + ic)*SS;
  float* pcI = ws + PCP + (size_t)((0*B + b)*4 + jc)*SS;
  float* pcT = ws + PCP + (size_t)((1*B + b)*4 + jc)*SS;

  __shared__ unsigned lpc[2][16][S];   // 16 KB: Pc accum, PERMUTED (c*32+q)
  __shared__ float    lpa[2][16][32];  //  4 KB: Pa row maxes
  __shared__ float    dred[16][3];

  // init lpc (4096 uints / 1024 threads = 4 each)
  {
    uint4* p = (uint4*)(&lpc[0][0][0]) + tid;
    *p = make_uint4(MAPF_NEGMAX, MAPF_NEGMAX, MAPF_NEGMAX, MAPF_NEGMAX);
  }
  __syncthreads();

  float4 pba = make_float4(NEG_INF, NEG_INF, NEG_INF, NEG_INF);
  float4 pbt = pba;
  float s_at = 0.f, s_aa = 0.f, s_tt = 0.f;

  for (int r = 0; r < 4; ++r) {
    // batch-issue the round's 8 loads before any use
    float4 A[4], T[4];
    #pragma unroll
    for (int q = 0; q < 4; ++q) {
      const size_t off = (size_t)(i0 + (r << 2) + q)*SS + (size_t)j*S + k0;
      A[q] = *(const float4*)(xin + off);
      T[q] = *(const float4*)(xtg + off);
    }
    #pragma unroll
    for (int q = 0; q < 4; ++q) {
      const int ii = (r << 2) + q;
      const float4 a = A[q];
      const float4 t = T[q];

      s_at = fmaf(a.x,t.x, fmaf(a.y,t.y, fmaf(a.z,t.z, fmaf(a.w,t.w, s_at))));
      s_aa = fmaf(a.x,a.x, fmaf(a.y,a.y, fmaf(a.z,a.z, fmaf(a.w,a.w, s_aa))));
      s_tt = fmaf(t.x,t.x, fmaf(t.y,t.y, fmaf(t.z,t.z, fmaf(t.w,t.w, s_tt))));

      // Pb accumulate over i (register)
      pba = max4(pba, a);
      pbt = max4(pbt, t);

      // Pa[i][j]: max over k = 32 kl lanes of this half-wave -> LDS buffer
      float rma = hmax4(a), rmt = hmax4(t);
      #pragma unroll
      for (int m = 16; m >= 1; m >>= 1) {
        rma = fmaxf(rma, __shfl_xor(rma, m, 64));
        rmt = fmaxf(rmt, __shfl_xor(rmt, m, 64));
      }
      if (kl == 0) { lpa[0][ii][jr] = rma; lpa[1][ii][jr] = rmt; }

      // Pc: combine the wave's jr-pair, then LDS atomicMax.
      // h-split: lanes 0-31 own the input plane, 32-63 the target plane.
      // Permuted element c*32+kl -> per-instruction banks = kl (2-way = free).
      const float4 pca = max4(a, shflx4(a, 32));
      const float4 pct = max4(t, shflx4(t, 32));
      const float4 pc  = h ? pct : pca;
      unsigned* plane = &lpc[h][ii][0];
      atomicMax(plane + 0*32 + kl, mapf(pc.x));
      atomicMax(plane + 1*32 + kl, mapf(pc.y));
      atomicMax(plane + 2*32 + kl, mapf(pc.z));
      atomicMax(plane + 3*32 + kl, mapf(pc.w));
    }
  }

  __syncthreads();   // all LDS atomics + lpa writes complete

  // Pc tail: 2t x 16ii x 32q, 4 k per thread. k=4q+c lives at c*32+q, so the
  // float4 store for k=4q..4q+3 reads elements {q, 32+q, 64+q, 96+q}.
  {
    const int t   = tid >> 9;
    const int rem = tid & 511;
    const int ii  = rem >> 5;
    const int q   = rem & 31;
    const float4 v = make_float4(unmapf(lpc[t][ii][ 0+q]), unmapf(lpc[t][ii][32+q]),
                                 unmapf(lpc[t][ii][64+q]), unmapf(lpc[t][ii][96+q]));
    *(float4*)((t ? pcT : pcI) + (size_t)(i0+ii)*S + (q << 2)) = v;
  }
  // Pa tail: 2t x 16ii x 32jj, coalesced dword stores
  {
    const int t   = tid >> 9;
    const int rem = tid & 511;
    const int ii  = rem >> 5;
    const int jj  = rem & 31;
    (t ? paT : paI)[(size_t)(i0+ii)*S + (jc << 5) + jj] = lpa[t][ii][jj];
  }

  // flush Pb partial [j][k] (max over this block's 16 i's) — float4 store
  *(float4*)(pbI + j*S + k0) = pba;
  *(float4*)(pbT + j*S + k0) = pbt;

  // dice partial: wave-reduce then per-block plain store (no atomics)
  float v0 = s_at, v1 = s_aa, v2 = s_tt;
  #pragma unroll
  for (int m = 32; m >= 1; m >>= 1) {
    v0 += __shfl_xor(v0, m, 64);
    v1 += __shfl_xor(v1, m, 64);
    v2 += __shfl_xor(v2, m, 64);
  }
  if ((tid & 63) == 0) { dred[w][0] = v0; dred[w][1] = v1; dred[w][2] = v2; }
  __syncthreads();
  if (tid == 0) {
    float a0 = 0.f, a1 = 0.f, a2 = 0.f;
    #pragma unroll
    for (int rr = 0; rr < 16; ++rr) { a0 += dred[rr][0]; a1 += dred[rr][1]; a2 += dred[rr][2]; }
    const int bid = jc + 4*ic + 32*b;   // 32 blocks per b
    ws[ACC_DICE + bid*3 + 0] = a0;
    ws[ACC_DICE + bid*3 + 1] = a1;
    ws[ACC_DICE + bid*3 + 2] = a2;
  }
}

// Phase 2: fused partial-reduce + pyramid max-pool at all 5 scales.
// One block per batch b; thread grid 16x16, each thread owns an 8x8 tile.
// Reads Pa (1 plane), Pb partials (8 planes), Pc partials (4 planes) per vol.
__global__ __launch_bounds__(256) void pool_loss_kernel(float* __restrict__ ws)
{
  const int b   = blockIdx.x;
  const int tid = threadIdx.x;
  const int tr  = tid >> 4;
  const int tc  = tid & 15;
  const int r0  = tr << 3;
  const int c0  = tc << 3;

  float s2[2][4][4];
  float s4[2][2][2];
  float s8[2], s16[2], s32[2];
  #pragma unroll
  for (int v = 0; v < 2; ++v) {
    #pragma unroll
    for (int y = 0; y < 4; ++y)
      #pragma unroll
      for (int x = 0; x < 4; ++x) s2[v][y][x] = 0.f;
    #pragma unroll
    for (int y = 0; y < 2; ++y)
      #pragma unroll
      for (int x = 0; x < 2; ++x) s4[v][y][x] = 0.f;
    s8[v] = 0.f; s16[v] = 0.f; s32[v] = 0.f;
  }

  #pragma unroll
  for (int t = 0; t < 3; ++t) {
    #pragma unroll
    for (int vol = 0; vol < 2; ++vol) {
      const int np = (t == 0) ? 1 : (t == 1) ? 8 : 4;
      const float* base =
        (t == 0) ? ws + PA  + (size_t)(vol*B + b)*SS :
        (t == 1) ? ws + PBP + (size_t)((vol*B + b)*8)*SS :
                   ws + PCP + (size_t)((vol*B + b)*4)*SS;
      float tile[8][8];
      #pragma unroll
      for (int r = 0; r < 8; ++r)
        #pragma unroll
        for (int c = 0; c < 8; ++c) tile[r][c] = NEG_INF;
      for (int p = 0; p < np; ++p) {
        const float* m = base + (size_t)p*SS;
        #pragma unroll
        for (int r = 0; r < 8; ++r) {
          const float4 a = *(const float4*)(m + (size_t)(r0 + r)*S + c0);
          const float4 c = *(const float4*)(m + (size_t)(r0 + r)*S + c0 + 4);
          tile[r][0]=fmaxf(tile[r][0],a.x); tile[r][1]=fmaxf(tile[r][1],a.y);
          tile[r][2]=fmaxf(tile[r][2],a.z); tile[r][3]=fmaxf(tile[r][3],a.w);
          tile[r][4]=fmaxf(tile[r][4],c.x); tile[r][5]=fmaxf(tile[r][5],c.y);
          tile[r][6]=fmaxf(tile[r][6],c.z); tile[r][7]=fmaxf(tile[r][7],c.w);
        }
      }
      float m2[4][4];
      #pragma unroll
      for (int y = 0; y < 4; ++y)
        #pragma unroll
        for (int x = 0; x < 4; ++x) {
          m2[y][x] = fmaxf(fmaxf(tile[2*y][2*x], tile[2*y][2*x+1]),
                           fmaxf(tile[2*y+1][2*x], tile[2*y+1][2*x+1]));
          s2[vol][y][x] += m2[y][x];
        }
      float m4[2][2];
      #pragma unroll
      for (int y = 0; y < 2; ++y)
        #pragma unroll
        for (int x = 0; x < 2; ++x) {
          m4[y][x] = fmaxf(fmaxf(m2[2*y][2*x], m2[2*y][2*x+1]),
                           fmaxf(m2[2*y+1][2*x], m2[2*y+1][2*x+1]));
          s4[vol][y][x] += m4[y][x];
        }
      float m8 = fmaxf(fmaxf(m4[0][0], m4[0][1]), fmaxf(m4[1][0], m4[1][1]));
      s8[vol] += m8;
      float m16 = m8;
      m16 = fmaxf(m16, __shfl_xor(m16, 1, 64));
      m16 = fmaxf(m16, __shfl_xor(m16, 16, 64));
      s16[vol] += m16;
      float m32 = m16;
      m32 = fmaxf(m32, __shfl_xor(m32, 2, 64));
      m32 = fmaxf(m32, __shfl_xor(m32, 32, 64));
      s32[vol] += m32;
    }
  }

  const float w0 = 1.f/(5.f*8.f*64.f*64.f);
  const float w1 = 1.f/(5.f*8.f*32.f*32.f);
  const float w2 = 1.f/(5.f*8.f*16.f*16.f);
  const float w3 = 1.f/(5.f*8.f*8.f*8.f);
  const float w4 = 1.f/(5.f*8.f*4.f*4.f);

  float l0 = 0.f;
  #pragma unroll
  for (int y = 0; y < 4; ++y)
    #pragma unroll
    for (int x = 0; x < 4; ++x) l0 += fabsf(s2[1][y][x] - s2[0][y][x]);
  float l1 = 0.f;
  #pragma unroll
  for (int y = 0; y < 2; ++y)
    #pragma unroll
    for (int x = 0; x < 2; ++x) l1 += fabsf(s4[1][y][x] - s4[0][y][x]);
  float part = l0*w0 + l1*w1 + fabsf(s8[1] - s8[0])*w2;
  if ((tid & 0x11) == 0) part += fabsf(s16[1] - s16[0])*w3;
  if ((tid & 0x33) == 0) part += fabsf(s32[1] - s32[0])*w4;

  #pragma unroll
  for (int m = 32; m >= 1; m >>= 1) part += __shfl_xor(part, m, 64);
  __shared__ float red[4];
  const int wid = tid >> 6;
  if ((tid & 63) == 0) red[wid] = part;
  __syncthreads();
  if (tid == 0) ws[ACC_LOSS + b] = red[0] + red[1] + red[2] + red[3];
}

// Phase 3: combine. 256 threads; 32-lane group per b reduces dice partials.
__global__ __launch_bounds__(256) void finalize_kernel(
    const float* __restrict__ ws, float* __restrict__ out)
{
  const int tid = threadIdx.x;
  __shared__ float fd[8];

  float v0 = ws[ACC_DICE + tid*3 + 0];
  float v1 = ws[ACC_DICE + tid*3 + 1];
  float v2 = ws[ACC_DICE + tid*3 + 2];
  #pragma unroll
  for (int m = 16; m >= 1; m >>= 1) {
    v0 += __shfl_xor(v0, m, 64);
    v1 += __shfl_xor(v1, m, 64);
    v2 += __shfl_xor(v2, m, 64);
  }
  if ((tid & 31) == 0) fd[tid >> 5] = (2.f*v0 + 1e-6f) / (v1 + v2);
  __syncthreads();
  if (tid == 0) {
    float topo = 0.f, dsum = 0.f;
    #pragma unroll
    for (int b = 0; b < B; ++b) { topo += ws[ACC_LOSS + b]; dsum += fd[b]; }
    out[0] = topo + (1.f - dsum / (float)B);
  }
}

extern "C" void kernel_launch(void* const* d_in, const int* in_sizes, int n_in,
                              void* d_out, int out_size, void* d_ws, size_t ws_size,
                              hipStream_t stream)
{
  const float* gin = (const float*)d_in[0];
  const float* gtg = (const float*)d_in[1];
  float* ws  = (float*)d_ws;
  float* out = (float*)d_out;

  dim3 g1(4, 8, B);
  proj_dice_kernel<<<g1, dim3(1024), 0, stream>>>(gin, gtg, ws);

  pool_loss_kernel<<<B, dim3(256), 0, stream>>>(ws);

  finalize_kernel<<<1, dim3(256), 0, stream>>>(ws, out);
}

// Round 13
// 43.546 us; speedup vs baseline: 2.0231x; 1.2313x over previous
//
#include <hip/hip_runtime.h>

#define S 128
#define SS (S*S)
#define B 8
#define BSS (B*SS)              // 131072 floats per [b][128][128] stack
#define NEG_INF (-3.402823466e+38f)

// ws layout (float elements). NO global atomics on maps, NO memset.
// ACC_LOSS: [b][half] topo partials (16)
// ACC_DICE: [bid(256)][{at,aa,tt}] (768)
// ACC_CNT : pool completion counter (1 uint, re-zeroed by proj each launch)
// PA : [vol][b][i][j]  exact                 (2*BSS)
// PBP: [vol][b][ic=8][j][k] partials         (2*8*8*SS)
// PCP: [vol][b][jc=4][i][k] partials         (2*8*4*SS)
#define ACC_LOSS 0
#define ACC_DICE 16
#define ACC_CNT  1008
#define PA   1024
#define PBP  (PA  + 2*BSS)
#define PCP  (PBP + 2*8*8*SS)

__device__ __forceinline__ float4 max4(float4 a, float4 b) {
  return make_float4(fmaxf(a.x,b.x), fmaxf(a.y,b.y), fmaxf(a.z,b.z), fmaxf(a.w,b.w));
}
__device__ __forceinline__ float hmax4(float4 a) {
  return fmaxf(fmaxf(a.x,a.y), fmaxf(a.z,a.w));
}
__device__ __forceinline__ float4 shflx4(float4 v, int m) {
  return make_float4(__shfl_xor(v.x,m,64), __shfl_xor(v.y,m,64),
                     __shfl_xor(v.z,m,64), __shfl_xor(v.w,m,64));
}

// Phase 1: stream channel-1 of both volumes once; projections + dice sums.
// R8-exact structure (best measured): grid (jc=4, ic=8, b=8) = 256 blocks,
// 1024 threads, 128 KB parity-double-buffered LDS, 4 in-loop barriers.
__global__ __launch_bounds__(1024, 4) void proj_dice_kernel(
    const float* __restrict__ gin, const float* __restrict__ gtg,
    float* __restrict__ ws)
{
  const int jc  = blockIdx.x;   // 0..3   j chunk of 32
  const int ic  = blockIdx.y;   // 0..7   i chunk of 16
  const int b   = blockIdx.z;   // 0..7
  const int tid = threadIdx.x;
  const int jr  = tid >> 5;     // 0..31
  const int kl  = tid & 31;     // 0..31
  const int j   = (jc << 5) + jr;
  const int i0  = ic << 4;
  const int k0  = kl << 2;
  const int w   = tid >> 6;     // wave 0..15
  const int h   = (tid >> 5) & 1;

  // re-arm the pool completion counter every launch (visible to the pool
  // dispatch via the dispatch boundary; solves poison-init determinism).
  if (tid == 0 && jc == 0 && ic == 0 && b == 0)
    ((unsigned*)ws)[ACC_CNT] = 0u;

  const float* __restrict__ xin = gin + (size_t)(2*b + 1) * (size_t)(S*SS);
  const float* __restrict__ xtg = gtg + (size_t)(2*b + 1) * (size_t)(S*SS);

  float* paI = ws + PA + (size_t)(0*B + b)*SS;
  float* paT = ws + PA + (size_t)(1*B + b)*SS;
  float* pbI = ws + PBP + (size_t)((0*B + b)*8 + ic)*SS;
  float* pbT = ws + PBP + (size_t)((1*B + b)*8 + ic)*SS;
  float* pcI = ws + PCP + (size_t)((0*B + b)*4 + jc)*SS;
  float* pcT = ws + PCP + (size_t)((1*B + b)*4 + jc)*SS;

  __shared__ float lpc[2][4][2][16][S];   // 128 KB: [parity][q][tensor][wave][k]
  __shared__ float dred[16][3];

  float4 pba = make_float4(NEG_INF, NEG_INF, NEG_INF, NEG_INF);
  float4 pbt = pba;
  float s_at = 0.f, s_aa = 0.f, s_tt = 0.f;

  for (int r = 0; r < 4; ++r) {
    const int par = r & 1;
    #pragma unroll
    for (int q = 0; q < 4; ++q) {
      const int i = i0 + (r << 2) + q;
      const size_t off = (size_t)i*SS + (size_t)j*S + k0;
      const float4 a = *(const float4*)(xin + off);
      const float4 t = *(const float4*)(xtg + off);

      s_at = fmaf(a.x,t.x, fmaf(a.y,t.y, fmaf(a.z,t.z, fmaf(a.w,t.w, s_at))));
      s_aa = fmaf(a.x,a.x, fmaf(a.y,a.y, fmaf(a.z,a.z, fmaf(a.w,a.w, s_aa))));
      s_tt = fmaf(t.x,t.x, fmaf(t.y,t.y, fmaf(t.z,t.z, fmaf(t.w,t.w, s_tt))));

      // Pb accumulate over i (register)
      pba = max4(pba, a);
      pbt = max4(pbt, t);

      // Pa[i][j]: max over k = 32 kl lanes of this half-wave
      float rma = hmax4(a), rmt = hmax4(t);
      #pragma unroll
      for (int m = 16; m >= 1; m >>= 1) {
        rma = fmaxf(rma, __shfl_xor(rma, m, 64));
        rmt = fmaxf(rmt, __shfl_xor(rmt, m, 64));
      }
      if (kl == 0) { paI[i*S + j] = rma; paT[i*S + j] = rmt; }

      // Pc wave partial: combine the wave's jr-pair, stash in LDS
      const float4 pca = max4(a, shflx4(a, 32));
      const float4 pct = max4(t, shflx4(t, 32));
      if (h == 0) {
        *(float4*)&lpc[par][q][0][w][k0] = pca;
        *(float4*)&lpc[par][q][1][w][k0] = pct;
      }
    }
    __syncthreads();
    {
      // tail: 1024 threads = 4 q x 2 tensors x 128 k -> plain store partial
      const int q  = tid >> 8;
      const int t  = (tid >> 7) & 1;
      const int k  = tid & 127;
      float m = lpc[par][q][t][0][k];
      #pragma unroll
      for (int rr = 1; rr < 16; ++rr) m = fmaxf(m, lpc[par][q][t][rr][k]);
      const int i = i0 + (r << 2) + q;
      (t ? pcT : pcI)[i*S + k] = m;
    }
    // no second barrier: next round writes the other parity half.
  }

  // flush Pb partial [j][k] (max over this block's 16 i's)
  *(float4*)(pbI + j*S + k0) = pba;
  *(float4*)(pbT + j*S + k0) = pbt;

  // dice partial: wave-reduce then per-block plain store (no atomics)
  float v0 = s_at, v1 = s_aa, v2 = s_tt;
  #pragma unroll
  for (int m = 32; m >= 1; m >>= 1) {
    v0 += __shfl_xor(v0, m, 64);
    v1 += __shfl_xor(v1, m, 64);
    v2 += __shfl_xor(v2, m, 64);
  }
  if ((tid & 63) == 0) { dred[w][0] = v0; dred[w][1] = v1; dred[w][2] = v2; }
  __syncthreads();
  if (tid == 0) {
    float a0 = 0.f, a1 = 0.f, a2 = 0.f;
    #pragma unroll
    for (int rr = 0; rr < 16; ++rr) { a0 += dred[rr][0]; a1 += dred[rr][1]; a2 += dred[rr][2]; }
    const int bid = jc + 4*ic + 32*b;   // 32 blocks per b
    ws[ACC_DICE + bid*3 + 0] = a0;
    ws[ACC_DICE + bid*3 + 1] = a1;
    ws[ACC_DICE + bid*3 + 2] = a2;
  }
}

// Phase 2: fused partial-reduce + pyramid max-pool + (last block) finalize.
// Grid (half=2, b=8) = 16 blocks, 128 threads. Each block owns a 128x64
// column-half (all pooling windows <=32 cols stay inside a half).
// Thread = (tr = tid>>3 in 0..15, tc = tid&7), owns an 8x8 tile.
// Last block to finish (agent-scope acq_rel counter) performs the dice
// finalize + output write — release/acquire gives cross-XCD visibility.
__global__ __launch_bounds__(128) void pool_loss_kernel(
    float* __restrict__ ws, float* __restrict__ out)
{
  const int half = blockIdx.x;   // 0..1
  const int b    = blockIdx.y;
  const int tid  = threadIdx.x;
  const int tr   = tid >> 3;     // 0..15
  const int tc   = tid & 7;      // 0..7
  const int r0   = tr << 3;
  const int c0   = (half << 6) + (tc << 3);

  float s2[2][4][4];
  float s4[2][2][2];
  float s8[2], s16[2], s32[2];
  #pragma unroll
  for (int v = 0; v < 2; ++v) {
    #pragma unroll
    for (int y = 0; y < 4; ++y)
      #pragma unroll
      for (int x = 0; x < 4; ++x) s2[v][y][x] = 0.f;
    #pragma unroll
    for (int y = 0; y < 2; ++y)
      #pragma unroll
      for (int x = 0; x < 2; ++x) s4[v][y][x] = 0.f;
    s8[v] = 0.f; s16[v] = 0.f; s32[v] = 0.f;
  }

  #pragma unroll
  for (int t = 0; t < 3; ++t) {
    #pragma unroll
    for (int vol = 0; vol < 2; ++vol) {
      const int np = (t == 0) ? 1 : (t == 1) ? 8 : 4;
      const float* base =
        (t == 0) ? ws + PA  + (size_t)(vol*B + b)*SS :
        (t == 1) ? ws + PBP + (size_t)((vol*B + b)*8)*SS :
                   ws + PCP + (size_t)((vol*B + b)*4)*SS;
      float tile[8][8];
      #pragma unroll
      for (int r = 0; r < 8; ++r)
        #pragma unroll
        for (int c = 0; c < 8; ++c) tile[r][c] = NEG_INF;
      for (int p = 0; p < np; ++p) {
        const float* m = base + (size_t)p*SS;
        #pragma unroll
        for (int r = 0; r < 8; ++r) {
          const float4 a = *(const float4*)(m + (size_t)(r0 + r)*S + c0);
          const float4 c = *(const float4*)(m + (size_t)(r0 + r)*S + c0 + 4);
          tile[r][0]=fmaxf(tile[r][0],a.x); tile[r][1]=fmaxf(tile[r][1],a.y);
          tile[r][2]=fmaxf(tile[r][2],a.z); tile[r][3]=fmaxf(tile[r][3],a.w);
          tile[r][4]=fmaxf(tile[r][4],c.x); tile[r][5]=fmaxf(tile[r][5],c.y);
          tile[r][6]=fmaxf(tile[r][6],c.z); tile[r][7]=fmaxf(tile[r][7],c.w);
        }
      }
      float m2[4][4];
      #pragma unroll
      for (int y = 0; y < 4; ++y)
        #pragma unroll
        for (int x = 0; x < 4; ++x) {
          m2[y][x] = fmaxf(fmaxf(tile[2*y][2*x], tile[2*y][2*x+1]),
                           fmaxf(tile[2*y+1][2*x], tile[2*y+1][2*x+1]));
          s2[vol][y][x] += m2[y][x];
        }
      float m4[2][2];
      #pragma unroll
      for (int y = 0; y < 2; ++y)
        #pragma unroll
        for (int x = 0; x < 2; ++x) {
          m4[y][x] = fmaxf(fmaxf(m2[2*y][2*x], m2[2*y][2*x+1]),
                           fmaxf(m2[2*y+1][2*x], m2[2*y+1][2*x+1]));
          s4[vol][y][x] += m4[y][x];
        }
      float m8 = fmaxf(fmaxf(m4[0][0], m4[0][1]), fmaxf(m4[1][0], m4[1][1]));
      s8[vol] += m8;
      float m16 = m8;                           // 16x16: partners tc^1, tr^1
      m16 = fmaxf(m16, __shfl_xor(m16, 1, 64));
      m16 = fmaxf(m16, __shfl_xor(m16, 8, 64));
      s16[vol] += m16;
      float m32 = m16;                          // 32x32: +tc^2, tr^2
      m32 = fmaxf(m32, __shfl_xor(m32, 2, 64));
      m32 = fmaxf(m32, __shfl_xor(m32, 16, 64));
      s32[vol] += m32;
    }
  }

  const float w0 = 1.f/(5.f*8.f*64.f*64.f);
  const float w1 = 1.f/(5.f*8.f*32.f*32.f);
  const float w2 = 1.f/(5.f*8.f*16.f*16.f);
  const float w3 = 1.f/(5.f*8.f*8.f*8.f);
  const float w4 = 1.f/(5.f*8.f*4.f*4.f);

  float l0 = 0.f;
  #pragma unroll
  for (int y = 0; y < 4; ++y)
    #pragma unroll
    for (int x = 0; x < 4; ++x) l0 += fabsf(s2[1][y][x] - s2[0][y][x]);
  float l1 = 0.f;
  #pragma unroll
  for (int y = 0; y < 2; ++y)
    #pragma unroll
    for (int x = 0; x < 2; ++x) l1 += fabsf(s4[1][y][x] - s4[0][y][x]);
  float part = l0*w0 + l1*w1 + fabsf(s8[1] - s8[0])*w2;
  if ((tid & 0x09) == 0) part += fabsf(s16[1] - s16[0])*w3;   // tr,tc even
  if ((tid & 0x1B) == 0) part += fabsf(s32[1] - s32[0])*w4;   // tr,tc %4==0

  #pragma unroll
  for (int m = 32; m >= 1; m >>= 1) part += __shfl_xor(part, m, 64);
  __shared__ float red[2];
  __shared__ int   isLast;
  if ((tid & 63) == 0) red[tid >> 6] = part;
  __syncthreads();
  if (tid == 0) {
    ws[ACC_LOSS + (b << 1) + half] = red[0] + red[1];
    // release own stores + count completion (agent scope = device-wide)
    unsigned old = __hip_atomic_fetch_add((unsigned*)ws + ACC_CNT, 1u,
                                          __ATOMIC_ACQ_REL,
                                          __HIP_MEMORY_SCOPE_AGENT);
    isLast = (old == 15u);
  }
  __syncthreads();
  if (!isLast) return;

  // ---- finalize (last pool block only; acquire above makes all other
  //      blocks' ACC_LOSS stores + proj's ACC_DICE stores visible) ----
  __shared__ float fd[8];
  {
    const int bf = tid >> 4;        // 0..7
    const int g  = tid & 15;        // 0..15, 2 triples each
    const int bid = (bf << 5) + (g << 1);
    float v0 = ws[ACC_DICE + bid*3 + 0] + ws[ACC_DICE + (bid+1)*3 + 0];
    float v1 = ws[ACC_DICE + bid*3 + 1] + ws[ACC_DICE + (bid+1)*3 + 1];
    float v2 = ws[ACC_DICE + bid*3 + 2] + ws[ACC_DICE + (bid+1)*3 + 2];
    #pragma unroll
    for (int m = 8; m >= 1; m >>= 1) {
      v0 += __shfl_xor(v0, m, 64);
      v1 += __shfl_xor(v1, m, 64);
      v2 += __shfl_xor(v2, m, 64);
    }
    if (g == 0) fd[bf] = (2.f*v0 + 1e-6f) / (v1 + v2);
  }
  __syncthreads();
  if (tid == 0) {
    float topo = 0.f, dsum = 0.f;
    #pragma unroll
    for (int x = 0; x < 16; ++x) topo += ws[ACC_LOSS + x];
    #pragma unroll
    for (int bb = 0; bb < B; ++bb) dsum += fd[bb];
    out[0] = topo + (1.f - dsum / (float)B);
  }
}

extern "C" void kernel_launch(void* const* d_in, const int* in_sizes, int n_in,
                              void* d_out, int out_size, void* d_ws, size_t ws_size,
                              hipStream_t stream)
{
  const float* gin = (const float*)d_in[0];
  const float* gtg = (const float*)d_in[1];
  float* ws  = (float*)d_ws;
  float* out = (float*)d_out;

  dim3 g1(4, 8, B);
  proj_dice_kernel<<<g1, dim3(1024), 0, stream>>>(gin, gtg, ws);

  pool_loss_kernel<<<dim3(2, B), dim3(128), 0, stream>>>(ws, out);
}

// Round 14
// 42.710 us; speedup vs baseline: 2.0627x; 1.0196x over previous
//
#include <hip/hip_runtime.h>

#define S 128
#define SS (S*S)
#define B 8
#define BSS (B*SS)              // 131072 floats per [b][128][128] stack
#define NEG_INF (-3.402823466e+38f)

// ws layout (float elements). NO global atomics on maps, NO memset.
// ACC_LOSS: [b][quarter] topo partials (32)
// ACC_DICE: [bid(256)][{at,aa,tt}] (768)
// ACC_CNT : pool completion counter (1 uint, re-zeroed by proj each launch)
// PA : [vol][b][i][j]  exact                 (2*BSS)
// PBP: [vol][b][ic=8][j][k] partials         (2*8*8*SS)
// PCP: [vol][b][jc=4][i][k] partials         (2*8*4*SS)
#define ACC_LOSS 0
#define ACC_DICE 32
#define ACC_CNT  1008
#define PA   1024
#define PBP  (PA  + 2*BSS)
#define PCP  (PBP + 2*8*8*SS)

__device__ __forceinline__ float4 max4(float4 a, float4 b) {
  return make_float4(fmaxf(a.x,b.x), fmaxf(a.y,b.y), fmaxf(a.z,b.z), fmaxf(a.w,b.w));
}
__device__ __forceinline__ float hmax4(float4 a) {
  return fmaxf(fmaxf(a.x,a.y), fmaxf(a.z,a.w));
}
__device__ __forceinline__ float4 shflx4(float4 v, int m) {
  return make_float4(__shfl_xor(v.x,m,64), __shfl_xor(v.y,m,64),
                     __shfl_xor(v.z,m,64), __shfl_xor(v.w,m,64));
}

// Phase 1: stream channel-1 of both volumes once; projections + dice sums.
// R8/R13-exact structure (best measured): grid (jc=4, ic=8, b=8) = 256 blocks,
// 1024 threads, 128 KB parity-double-buffered LDS, 4 in-loop barriers.
__global__ __launch_bounds__(1024, 4) void proj_dice_kernel(
    const float* __restrict__ gin, const float* __restrict__ gtg,
    float* __restrict__ ws)
{
  const int jc  = blockIdx.x;   // 0..3   j chunk of 32
  const int ic  = blockIdx.y;   // 0..7   i chunk of 16
  const int b   = blockIdx.z;   // 0..7
  const int tid = threadIdx.x;
  const int jr  = tid >> 5;     // 0..31
  const int kl  = tid & 31;     // 0..31
  const int j   = (jc << 5) + jr;
  const int i0  = ic << 4;
  const int k0  = kl << 2;
  const int w   = tid >> 6;     // wave 0..15
  const int h   = (tid >> 5) & 1;

  // re-arm the pool completion counter every launch (visible to the pool
  // dispatch via the dispatch boundary; solves poison-init determinism).
  if (tid == 0 && jc == 0 && ic == 0 && b == 0)
    ((unsigned*)ws)[ACC_CNT] = 0u;

  const float* __restrict__ xin = gin + (size_t)(2*b + 1) * (size_t)(S*SS);
  const float* __restrict__ xtg = gtg + (size_t)(2*b + 1) * (size_t)(S*SS);

  float* paI = ws + PA + (size_t)(0*B + b)*SS;
  float* paT = ws + PA + (size_t)(1*B + b)*SS;
  float* pbI = ws + PBP + (size_t)((0*B + b)*8 + ic)*SS;
  float* pbT = ws + PBP + (size_t)((1*B + b)*8 + ic)*SS;
  float* pcI = ws + PCP + (size_t)((0*B + b)*4 + jc)*SS;
  float* pcT = ws + PCP + (size_t)((1*B + b)*4 + jc)*SS;

  __shared__ float lpc[2][4][2][16][S];   // 128 KB: [parity][q][tensor][wave][k]
  __shared__ float dred[16][3];

  float4 pba = make_float4(NEG_INF, NEG_INF, NEG_INF, NEG_INF);
  float4 pbt = pba;
  float s_at = 0.f, s_aa = 0.f, s_tt = 0.f;

  for (int r = 0; r < 4; ++r) {
    const int par = r & 1;
    #pragma unroll
    for (int q = 0; q < 4; ++q) {
      const int i = i0 + (r << 2) + q;
      const size_t off = (size_t)i*SS + (size_t)j*S + k0;
      const float4 a = *(const float4*)(xin + off);
      const float4 t = *(const float4*)(xtg + off);

      s_at = fmaf(a.x,t.x, fmaf(a.y,t.y, fmaf(a.z,t.z, fmaf(a.w,t.w, s_at))));
      s_aa = fmaf(a.x,a.x, fmaf(a.y,a.y, fmaf(a.z,a.z, fmaf(a.w,a.w, s_aa))));
      s_tt = fmaf(t.x,t.x, fmaf(t.y,t.y, fmaf(t.z,t.z, fmaf(t.w,t.w, s_tt))));

      // Pb accumulate over i (register)
      pba = max4(pba, a);
      pbt = max4(pbt, t);

      // Pa[i][j]: max over k = 32 kl lanes of this half-wave
      float rma = hmax4(a), rmt = hmax4(t);
      #pragma unroll
      for (int m = 16; m >= 1; m >>= 1) {
        rma = fmaxf(rma, __shfl_xor(rma, m, 64));
        rmt = fmaxf(rmt, __shfl_xor(rmt, m, 64));
      }
      if (kl == 0) { paI[i*S + j] = rma; paT[i*S + j] = rmt; }

      // Pc wave partial: combine the wave's jr-pair, stash in LDS
      const float4 pca = max4(a, shflx4(a, 32));
      const float4 pct = max4(t, shflx4(t, 32));
      if (h == 0) {
        *(float4*)&lpc[par][q][0][w][k0] = pca;
        *(float4*)&lpc[par][q][1][w][k0] = pct;
      }
    }
    __syncthreads();
    {
      // tail: 1024 threads = 4 q x 2 tensors x 128 k -> plain store partial
      const int q  = tid >> 8;
      const int t  = (tid >> 7) & 1;
      const int k  = tid & 127;
      float m = lpc[par][q][t][0][k];
      #pragma unroll
      for (int rr = 1; rr < 16; ++rr) m = fmaxf(m, lpc[par][q][t][rr][k]);
      const int i = i0 + (r << 2) + q;
      (t ? pcT : pcI)[i*S + k] = m;
    }
    // no second barrier: next round writes the other parity half.
  }

  // flush Pb partial [j][k] (max over this block's 16 i's)
  *(float4*)(pbI + j*S + k0) = pba;
  *(float4*)(pbT + j*S + k0) = pbt;

  // dice partial: wave-reduce then per-block plain store (no atomics)
  float v0 = s_at, v1 = s_aa, v2 = s_tt;
  #pragma unroll
  for (int m = 32; m >= 1; m >>= 1) {
    v0 += __shfl_xor(v0, m, 64);
    v1 += __shfl_xor(v1, m, 64);
    v2 += __shfl_xor(v2, m, 64);
  }
  if ((tid & 63) == 0) { dred[w][0] = v0; dred[w][1] = v1; dred[w][2] = v2; }
  __syncthreads();
  if (tid == 0) {
    float a0 = 0.f, a1 = 0.f, a2 = 0.f;
    #pragma unroll
    for (int rr = 0; rr < 16; ++rr) { a0 += dred[rr][0]; a1 += dred[rr][1]; a2 += dred[rr][2]; }
    const int bid = jc + 4*ic + 32*b;   // 32 blocks per b
    ws[ACC_DICE + bid*3 + 0] = a0;
    ws[ACC_DICE + bid*3 + 1] = a1;
    ws[ACC_DICE + bid*3 + 2] = a2;
  }
}

// Phase 2: fused partial-reduce + pyramid max-pool + (last block) finalize.
// Grid (quarter=4, b=8) = 32 blocks, 64 threads (1 wave). Each block owns a
// 128x32 column-quarter (all pooling windows <=32 cols stay inside it).
// Lane = (tr = lane>>2 in 0..15, tc = lane&3), owns an 8x8 tile.
// k=2,4,8 in-registers; k=16 via shfl_xor {1,4}; k=32 via {2,8}.
// Last block to finish (agent-scope acq_rel counter) does dice finalize +
// output write — release/acquire gives cross-XCD visibility.
__global__ __launch_bounds__(64) void pool_loss_kernel(
    float* __restrict__ ws, float* __restrict__ out)
{
  const int quarter = blockIdx.x;   // 0..3
  const int b       = blockIdx.y;
  const int tid     = threadIdx.x;  // 0..63
  const int tr      = tid >> 2;     // 0..15
  const int tc      = tid & 3;      // 0..3
  const int r0      = tr << 3;
  const int c0      = (quarter << 5) + (tc << 3);

  float s2[2][4][4];
  float s4[2][2][2];
  float s8[2], s16[2], s32[2];
  #pragma unroll
  for (int v = 0; v < 2; ++v) {
    #pragma unroll
    for (int y = 0; y < 4; ++y)
      #pragma unroll
      for (int x = 0; x < 4; ++x) s2[v][y][x] = 0.f;
    #pragma unroll
    for (int y = 0; y < 2; ++y)
      #pragma unroll
      for (int x = 0; x < 2; ++x) s4[v][y][x] = 0.f;
    s8[v] = 0.f; s16[v] = 0.f; s32[v] = 0.f;
  }

  #pragma unroll
  for (int t = 0; t < 3; ++t) {
    #pragma unroll
    for (int vol = 0; vol < 2; ++vol) {
      const int np = (t == 0) ? 1 : (t == 1) ? 8 : 4;
      const float* base =
        (t == 0) ? ws + PA  + (size_t)(vol*B + b)*SS :
        (t == 1) ? ws + PBP + (size_t)((vol*B + b)*8)*SS :
                   ws + PCP + (size_t)((vol*B + b)*4)*SS;
      float tile[8][8];
      #pragma unroll
      for (int r = 0; r < 8; ++r)
        #pragma unroll
        for (int c = 0; c < 8; ++c) tile[r][c] = NEG_INF;
      for (int p = 0; p < np; ++p) {
        const float* m = base + (size_t)p*SS;
        #pragma unroll
        for (int r = 0; r < 8; ++r) {
          const float4 a = *(const float4*)(m + (size_t)(r0 + r)*S + c0);
          const float4 c = *(const float4*)(m + (size_t)(r0 + r)*S + c0 + 4);
          tile[r][0]=fmaxf(tile[r][0],a.x); tile[r][1]=fmaxf(tile[r][1],a.y);
          tile[r][2]=fmaxf(tile[r][2],a.z); tile[r][3]=fmaxf(tile[r][3],a.w);
          tile[r][4]=fmaxf(tile[r][4],c.x); tile[r][5]=fmaxf(tile[r][5],c.y);
          tile[r][6]=fmaxf(tile[r][6],c.z); tile[r][7]=fmaxf(tile[r][7],c.w);
        }
      }
      float m2[4][4];
      #pragma unroll
      for (int y = 0; y < 4; ++y)
        #pragma unroll
        for (int x = 0; x < 4; ++x) {
          m2[y][x] = fmaxf(fmaxf(tile[2*y][2*x], tile[2*y][2*x+1]),
                           fmaxf(tile[2*y+1][2*x], tile[2*y+1][2*x+1]));
          s2[vol][y][x] += m2[y][x];
        }
      float m4[2][2];
      #pragma unroll
      for (int y = 0; y < 2; ++y)
        #pragma unroll
        for (int x = 0; x < 2; ++x) {
          m4[y][x] = fmaxf(fmaxf(m2[2*y][2*x], m2[2*y][2*x+1]),
                           fmaxf(m2[2*y+1][2*x], m2[2*y+1][2*x+1]));
          s4[vol][y][x] += m4[y][x];
        }
      float m8 = fmaxf(fmaxf(m4[0][0], m4[0][1]), fmaxf(m4[1][0], m4[1][1]));
      s8[vol] += m8;
      float m16 = m8;                           // 16x16: partners tc^1, tr^1
      m16 = fmaxf(m16, __shfl_xor(m16, 1, 64));
      m16 = fmaxf(m16, __shfl_xor(m16, 4, 64));
      s16[vol] += m16;
      float m32 = m16;                          // 32x32: +tc^2, tr^2
      m32 = fmaxf(m32, __shfl_xor(m32, 2, 64));
      m32 = fmaxf(m32, __shfl_xor(m32, 8, 64));
      s32[vol] += m32;
    }
  }

  const float w0 = 1.f/(5.f*8.f*64.f*64.f);
  const float w1 = 1.f/(5.f*8.f*32.f*32.f);
  const float w2 = 1.f/(5.f*8.f*16.f*16.f);
  const float w3 = 1.f/(5.f*8.f*8.f*8.f);
  const float w4 = 1.f/(5.f*8.f*4.f*4.f);

  float l0 = 0.f;
  #pragma unroll
  for (int y = 0; y < 4; ++y)
    #pragma unroll
    for (int x = 0; x < 4; ++x) l0 += fabsf(s2[1][y][x] - s2[0][y][x]);
  float l1 = 0.f;
  #pragma unroll
  for (int y = 0; y < 2; ++y)
    #pragma unroll
    for (int x = 0; x < 2; ++x) l1 += fabsf(s4[1][y][x] - s4[0][y][x]);
  float part = l0*w0 + l1*w1 + fabsf(s8[1] - s8[0])*w2;
  if ((tid & 0x05) == 0) part += fabsf(s16[1] - s16[0])*w3;   // tc,tr even
  if ((tid & 0x0F) == 0) part += fabsf(s32[1] - s32[0])*w4;   // tc==0, tr%4==0

  #pragma unroll
  for (int m = 32; m >= 1; m >>= 1) part += __shfl_xor(part, m, 64);
  __shared__ int isLast;
  if (tid == 0) {
    ws[ACC_LOSS + (b << 2) + quarter] = part;
    // release own stores + count completion (agent scope = device-wide)
    unsigned old = __hip_atomic_fetch_add((unsigned*)ws + ACC_CNT, 1u,
                                          __ATOMIC_ACQ_REL,
                                          __HIP_MEMORY_SCOPE_AGENT);
    isLast = (old == 31u);
  }
  __syncthreads();
  if (!isLast) return;

  // ---- finalize (last pool block only; acquire above makes all other
  //      blocks' ACC_LOSS stores + proj's ACC_DICE stores visible) ----
  // 64 threads: thread = (bf = tid>>3 in 0..7, g = tid&7); each sums 4
  // consecutive dice triples of batch bf, then 3-step shfl over g.
  __shared__ float fd[8];
  {
    const int bf  = tid >> 3;       // 0..7
    const int g   = tid & 7;        // 0..7
    const int bid = (bf << 5) + (g << 2);
    float v0 = 0.f, v1 = 0.f, v2 = 0.f;
    #pragma unroll
    for (int u = 0; u < 4; ++u) {
      v0 += ws[ACC_DICE + (bid+u)*3 + 0];
      v1 += ws[ACC_DICE + (bid+u)*3 + 1];
      v2 += ws[ACC_DICE + (bid+u)*3 + 2];
    }
    #pragma unroll
    for (int m = 4; m >= 1; m >>= 1) {
      v0 += __shfl_xor(v0, m, 64);
      v1 += __shfl_xor(v1, m, 64);
      v2 += __shfl_xor(v2, m, 64);
    }
    if (g == 0) fd[bf] = (2.f*v0 + 1e-6f) / (v1 + v2);
  }
  __syncthreads();
  if (tid == 0) {
    float topo = 0.f, dsum = 0.f;
    #pragma unroll
    for (int x = 0; x < 32; ++x) topo += ws[ACC_LOSS + x];
    #pragma unroll
    for (int bb = 0; bb < B; ++bb) dsum += fd[bb];
    out[0] = topo + (1.f - dsum / (float)B);
  }
}

extern "C" void kernel_launch(void* const* d_in, const int* in_sizes, int n_in,
                              void* d_out, int out_size, void* d_ws, size_t ws_size,
                              hipStream_t stream)
{
  const float* gin = (const float*)d_in[0];
  const float* gtg = (const float*)d_in[1];
  float* ws  = (float*)d_ws;
  float* out = (float*)d_out;

  dim3 g1(4, 8, B);
  proj_dice_kernel<<<g1, dim3(1024), 0, stream>>>(gin, gtg, ws);

  pool_loss_kernel<<<dim3(4, B), dim3(64), 0, stream>>>(ws, out);
}